// Round 4
// baseline (2527.889 us; speedup 1.0000x reference)
//
#include <hip/hip_runtime.h>
#include <hip/hip_bf16.h>

#define BATCH 16384
#define NLEVS 60
#define NHID  64
#define ROWS_PER_BLOCK 64
#define UPS 8                                  // units per slice
#define THREADS 512                            // 64 rows x 8 slices
#define NBLOCKS (BATCH / ROWS_PER_BLOCK)       // 256

// d_out element offsets (f32 elements): (out, out_sfc, mem_new) flat
#define SFC_OFF (BATCH * NLEVS * 4)            // 3,932,160
#define MEM_OFF (SFC_OFF + BATCH * 3)          // 3,981,312

// ws layout (floats): [0,256) bc1  [256,512) bc2  [512,768) Wof  [768,772) bof
// rnn1out scratch starts at byte 65536.
#define WS_R1_BYTE_OFF 65536

typedef unsigned int uint;

__device__ __forceinline__ float bflo(uint u) {
    union { uint i; float f; } v; v.i = u << 16; return v.f;
}
__device__ __forceinline__ float bfhi(uint u) {
    union { uint i; float f; } v; v.i = u & 0xffff0000u; return v.f;
}
__device__ __forceinline__ float sigm(float x) {
    float e = __builtin_amdgcn_exp2f(-1.44269504f * x);
    return __builtin_amdgcn_rcpf(1.0f + e);
}
__device__ __forceinline__ float tanh_(float x) {
    float ax = fabsf(x);
    float e  = __builtin_amdgcn_exp2f(-2.88539008f * ax);   // exp(-2|x|)
    float t  = (1.0f - e) * __builtin_amdgcn_rcpf(1.0f + e);
    return copysignf(t, x);
}

// Precompute combined biases and fused output head: Wof = Wout@Wlat (4x64),
// bof = Wout@blat + bout (4). All f32, exact.
__global__ void setup_kernel(const float* __restrict__ b1ih, const float* __restrict__ b1hh,
                             const float* __restrict__ b2ih, const float* __restrict__ b2hh,
                             const float* __restrict__ Wlat, const float* __restrict__ blat,
                             const float* __restrict__ Wout, const float* __restrict__ bout,
                             float* __restrict__ ws) {
    int t = threadIdx.x;                        // 256 threads
    ws[t]       = b1ih[t] + b1hh[t];
    ws[256 + t] = b2ih[t] + b2hh[t];
    int o = t >> 6, k = t & 63;
    float s = 0.f;
    for (int m = 0; m < 16; ++m) s += Wout[o * 16 + m] * Wlat[m * 64 + k];
    ws[512 + t] = s;
    if (t < 4) {
        float s2 = bout[t];
        for (int m = 0; m < 16; ++m) s2 += Wout[t * 16 + m] * blat[m];
        ws[768 + t] = s2;
    }
}

template <bool F32STORE>
__global__ __launch_bounds__(THREADS, 2)
void lstm_main(const float* __restrict__ in_main,   // (B,60,4)
               const float* __restrict__ in_aux,    // (B,3)
               const float* __restrict__ in_mem,    // (B,60,16)
               const float* __restrict__ Wsfc1, const float* __restrict__ bsfc1,
               const float* __restrict__ Wsfc2, const float* __restrict__ bsfc2,
               const float* __restrict__ Wtoa1, const float* __restrict__ btoa1,
               const float* __restrict__ Wtoa2, const float* __restrict__ btoa2,
               const float* __restrict__ W1ih, const float* __restrict__ W1hh,
               const float* __restrict__ W2ih, const float* __restrict__ W2hh,
               const float* __restrict__ Wlat, const float* __restrict__ blat,
               const float* __restrict__ Wsfco, const float* __restrict__ bsfco,
               const float* __restrict__ wsc,       // bc1,bc2,Wof,bof
               void* __restrict__ r1ws,             // rnn1out scratch (chunk-local)
               int b_off,                           // first batch row of this chunk
               float* __restrict__ out) {
    __shared__ float h_lds[2][ROWS_PER_BLOCK][NHID + 1];   // double buffer, pad 65
    __shared__ float c_lds[ROWS_PER_BLOCK][NHID + 1];

    const int tid   = threadIdx.x;
    const int slice = __builtin_amdgcn_readfirstlane(tid >> 6);   // wave-uniform
    const int r     = tid & 63;
    const int b     = b_off + blockIdx.x * ROWS_PER_BLOCK + r;
    const int bl    = b - b_off;                  // chunk-local row for r1ws
    const int j0    = slice * UPS;

    const float a0 = in_aux[b * 3 + 0];
    const float a1 = in_aux[b * 3 + 1];
    const float a2 = in_aux[b * 3 + 2];

    // ---- LSTM1 init: h0 = tanh(aux@Wsfc1^T+b) (full per-thread), c0 own units
    float h_regs[NHID];
#pragma unroll
    for (int j = 0; j < NHID; ++j) {
        float s = fmaf(a2, Wsfc1[j * 3 + 2], bsfc1[j]);
        s = fmaf(a1, Wsfc1[j * 3 + 1], s);
        s = fmaf(a0, Wsfc1[j * 3 + 0], s);
        h_regs[j] = tanh_(s);
    }
    for (int u = 0; u < UPS; ++u) {
        int j = j0 + u;
        float s = fmaf(a2, Wsfc2[j * 3 + 2], bsfc2[j]);
        s = fmaf(a1, Wsfc2[j * 3 + 1], s);
        s = fmaf(a0, Wsfc2[j * 3 + 0], s);
        c_lds[r][j] = tanh_(s);
    }

    const float* bc1 = wsc;

    // ---- LSTM1: step t processes lev=59-t; output -> rnn1out[bl][lev]
    for (int t = 0; t < NLEVS; ++t) {
        const int lev = 59 - t;
        float x[20];
        {
            const float4 m4 = *(const float4*)(in_main + ((size_t)b * NLEVS + lev) * 4);
            x[0] = m4.x; x[1] = m4.y; x[2] = m4.z; x[3] = m4.w;
            const float4* mm = (const float4*)(in_mem + ((size_t)b * NLEVS + lev) * 16);
#pragma unroll
            for (int q = 0; q < 4; ++q) {
                float4 v = mm[q];
                x[4 + q * 4] = v.x; x[5 + q * 4] = v.y; x[6 + q * 4] = v.z; x[7 + q * 4] = v.w;
            }
        }
        for (int u = 0; u < UPS; ++u) {
            const int j = j0 + u;
            float ai = bc1[j], af = bc1[64 + j], ag = bc1[128 + j], ao = bc1[192 + j];
            const float* Wi = W1ih + j * 20;     // gate rows: (g*64+j)*20
#pragma unroll
            for (int k = 0; k < 20; ++k) {
                ai = fmaf(Wi[k], x[k], ai);
                af = fmaf(Wi[64 * 20 + k], x[k], af);
                ag = fmaf(Wi[128 * 20 + k], x[k], ag);
                ao = fmaf(Wi[192 * 20 + k], x[k], ao);
            }
            const float* Wh = W1hh + j * 64;
#pragma unroll
            for (int k = 0; k < NHID; ++k) {
                ai = fmaf(Wh[k], h_regs[k], ai);
                af = fmaf(Wh[64 * 64 + k], h_regs[k], af);
                ag = fmaf(Wh[128 * 64 + k], h_regs[k], ag);
                ao = fmaf(Wh[192 * 64 + k], h_regs[k], ao);
            }
            float c = c_lds[r][j];
            c = sigm(af) * c + sigm(ai) * tanh_(ag);
            float hn = sigm(ao) * tanh_(c);
            c_lds[r][j] = c;
            if (F32STORE)
                ((float*)r1ws)[((size_t)bl * NLEVS + lev) * NHID + j] = hn;
            else
                ((__hip_bfloat16*)r1ws)[((size_t)bl * NLEVS + lev) * NHID + j] = __float2bfloat16(hn);
            h_lds[t & 1][r][j] = hn;
        }
        __syncthreads();
#pragma unroll
        for (int k = 0; k < NHID; ++k) h_regs[k] = h_lds[t & 1][r][k];
    }

    // ---- LSTM2 init: h0 = toa*Wtoa2+btoa2 (full), c0 = toa*Wtoa1+btoa1 (own)
    const float toa = a1;
#pragma unroll
    for (int j = 0; j < NHID; ++j) h_regs[j] = fmaf(toa, Wtoa2[j], btoa2[j]);
    for (int u = 0; u < UPS; ++u) {
        int j = j0 + u;
        c_lds[r][j] = fmaf(toa, Wtoa1[j], btoa1[j]);
    }

    const float* bc2 = wsc + 256;
    const float* Wof = wsc + 512;
    const float* bof = wsc + 768;

    // ---- LSTM2: forward levs, fused heads per lev
    for (int lev = 0; lev < NLEVS; ++lev) {
        float x2[NHID];
        if (F32STORE) {
            const float4* p = (const float4*)((const float*)r1ws + ((size_t)bl * NLEVS + lev) * NHID);
#pragma unroll
            for (int q = 0; q < 16; ++q) {
                float4 v = p[q];
                x2[q * 4 + 0] = v.x; x2[q * 4 + 1] = v.y; x2[q * 4 + 2] = v.z; x2[q * 4 + 3] = v.w;
            }
        } else {
            const uint4* p = (const uint4*)((const __hip_bfloat16*)r1ws + ((size_t)bl * NLEVS + lev) * NHID);
#pragma unroll
            for (int q = 0; q < 8; ++q) {
                uint4 v = p[q];
                x2[q * 8 + 0] = bflo(v.x); x2[q * 8 + 1] = bfhi(v.x);
                x2[q * 8 + 2] = bflo(v.y); x2[q * 8 + 3] = bfhi(v.y);
                x2[q * 8 + 4] = bflo(v.z); x2[q * 8 + 5] = bfhi(v.z);
                x2[q * 8 + 6] = bflo(v.w); x2[q * 8 + 7] = bfhi(v.w);
            }
        }
        for (int u = 0; u < UPS; ++u) {
            const int j = j0 + u;
            float ai = bc2[j], af = bc2[64 + j], ag = bc2[128 + j], ao = bc2[192 + j];
            const float* Wi = W2ih + j * 64;
#pragma unroll
            for (int k = 0; k < NHID; ++k) {
                ai = fmaf(Wi[k], x2[k], ai);
                af = fmaf(Wi[64 * 64 + k], x2[k], af);
                ag = fmaf(Wi[128 * 64 + k], x2[k], ag);
                ao = fmaf(Wi[192 * 64 + k], x2[k], ao);
            }
            const float* Wh = W2hh + j * 64;
#pragma unroll
            for (int k = 0; k < NHID; ++k) {
                ai = fmaf(Wh[k], h_regs[k], ai);
                af = fmaf(Wh[64 * 64 + k], h_regs[k], af);
                ag = fmaf(Wh[128 * 64 + k], h_regs[k], ag);
                ao = fmaf(Wh[192 * 64 + k], h_regs[k], ao);
            }
            float c = c_lds[r][j];
            c = sigm(af) * c + sigm(ai) * tanh_(ag);
            float hn = sigm(ao) * tanh_(c);
            c_lds[r][j] = c;
            h_lds[lev & 1][r][j] = hn;
        }
        __syncthreads();
#pragma unroll
        for (int k = 0; k < NHID; ++k) h_regs[k] = h_lds[lev & 1][r][k];  // fresh h2

        // latent -> mem_new (2 per slice)
#pragma unroll
        for (int mm = 0; mm < 2; ++mm) {
            const int m = slice * 2 + mm;
            float s = blat[m];
#pragma unroll
            for (int k = 0; k < NHID; ++k) s = fmaf(Wlat[m * 64 + k], h_regs[k], s);
            out[MEM_OFF + ((size_t)b * NLEVS + lev) * 16 + m] = tanh_(s);
        }
        // out (fused Wout@Wlat) — slices 0..3, one output each
        if (slice < 4) {
            float s = bof[slice];
#pragma unroll
            for (int k = 0; k < NHID; ++k) s = fmaf(Wof[slice * 64 + k], h_regs[k], s);
            out[((size_t)b * NLEVS + lev) * 4 + slice] = s;
        }
        // out_sfc at last lev — slices 4..6, one output each
        if (lev == 59 && slice >= 4 && slice < 7) {
            const int o = slice - 4;
            float s = bsfco[o];
#pragma unroll
            for (int k = 0; k < NHID; ++k) s = fmaf(Wsfco[o * 64 + k], h_regs[k], s);
            out[SFC_OFF + (size_t)b * 3 + o] = s;
        }
    }
}

extern "C" void kernel_launch(void* const* d_in, const int* in_sizes, int n_in,
                              void* d_out, int out_size, void* d_ws, size_t ws_size,
                              hipStream_t stream) {
    const float* in_main = (const float*)d_in[0];
    const float* in_aux  = (const float*)d_in[1];
    const float* in_mem  = (const float*)d_in[2];
    const float* Wsfc1   = (const float*)d_in[3];
    const float* bsfc1   = (const float*)d_in[4];
    const float* Wsfc2   = (const float*)d_in[5];
    const float* bsfc2   = (const float*)d_in[6];
    const float* Wtoa1   = (const float*)d_in[7];
    const float* btoa1   = (const float*)d_in[8];
    const float* Wtoa2   = (const float*)d_in[9];
    const float* btoa2   = (const float*)d_in[10];
    const float* W1ih    = (const float*)d_in[11];
    const float* W1hh    = (const float*)d_in[12];
    const float* b1ih    = (const float*)d_in[13];
    const float* b1hh    = (const float*)d_in[14];
    const float* W2ih    = (const float*)d_in[15];
    const float* W2hh    = (const float*)d_in[16];
    const float* b2ih    = (const float*)d_in[17];
    const float* b2hh    = (const float*)d_in[18];
    const float* Wlat    = (const float*)d_in[19];
    const float* blat    = (const float*)d_in[20];
    const float* Wout    = (const float*)d_in[21];
    const float* bout    = (const float*)d_in[22];
    const float* Wsfco   = (const float*)d_in[23];
    const float* bsfco   = (const float*)d_in[24];
    float* out           = (float*)d_out;          // reference output dtype = f32

    float* wsc  = (float*)d_ws;
    void*  r1ws = (char*)d_ws + WS_R1_BYTE_OFF;
    const size_t avail = (ws_size > WS_R1_BYTE_OFF) ? (ws_size - WS_R1_BYTE_OFF) : 0;
    const size_t per_row_f32  = (size_t)NLEVS * NHID * 4;   // 15360 B
    const size_t per_row_bf16 = (size_t)NLEVS * NHID * 2;   // 7680 B

    setup_kernel<<<1, 256, 0, stream>>>(b1ih, b1hh, b2ih, b2hh, Wlat, blat, Wout, bout, wsc);

#define LAUNCH(F32S, GRID, BOFF)                                                  \
    lstm_main<F32S><<<GRID, THREADS, 0, stream>>>(                                \
        in_main, in_aux, in_mem, Wsfc1, bsfc1, Wsfc2, bsfc2, Wtoa1, btoa1,        \
        Wtoa2, btoa2, W1ih, W1hh, W2ih, W2hh, Wlat, blat, Wsfco, bsfco,           \
        wsc, r1ws, BOFF, out)

    if (avail >= (size_t)BATCH * per_row_f32) {
        LAUNCH(true, NBLOCKS, 0);
    } else if (avail >= (size_t)BATCH * per_row_bf16) {
        LAUNCH(false, NBLOCKS, 0);
    } else {
        // Chunked fallback: rows per chunk sized to workspace, multiple of 64.
        size_t rows = avail / per_row_bf16;
        rows &= ~(size_t)63;
        if (rows < 64) rows = 64;               // minimum one block (491,520 B)
        if (rows > BATCH) rows = BATCH;
        for (int off = 0; off < BATCH; off += (int)rows) {
            int nrows = (int)rows;
            if (off + nrows > BATCH) nrows = BATCH - off;
            LAUNCH(false, nrows / ROWS_PER_BLOCK, off);
        }
    }
#undef LAUNCH
}